// Round 3
// baseline (236.361 us; speedup 1.0000x reference)
//
#include <hip/hip_runtime.h>
#include <hip/hip_bf16.h>

#define NF    32
#define ED    128
#define NBATCH 2048
#define NPAIRS 496
#define BM    128
#define MBLKS (NBATCH / BM)          // 16
#define NWG   (NPAIRS * MBLKS)       // 7936

typedef __attribute__((ext_vector_type(8))) short  short8;   // 8 bf16 = 4 VGPR (MFMA A/B frag)
typedef __attribute__((ext_vector_type(4))) float  f32x4;    // MFMA C/D frag

// Native conversion -> compiler emits v_cvt_pk_bf16_f32 for adjacent pairs (m240)
__device__ __forceinline__ short f2bf(float x) {
    union { __hip_bfloat16 b; short s; } v;
    v.b = __float2bfloat16(x);
    return v.s;
}

// LDS byte layout (both tiles): row-major 128 rows x 256 B, swizzled:
//   byte(row, col_byte) = row*256 + (col_byte ^ ((row & 15) << 4))
// -> fragment reads (16 lanes, 16 consecutive rows, same col slot) hit 16
//    distinct 16B slots => conflict-free ds_read_b128.

__global__ __launch_bounds__(512, 4)
void bilinear_mfma_kernel(const float* __restrict__ femb,
                          const float* __restrict__ W,
                          float* __restrict__ out)
{
    __shared__ unsigned char ldsA[128 * 256];  // vi tile: [b_local][d] bf16, swizzled
    __shared__ unsigned char ldsB[128 * 256];  // W tile:  [e][d] bf16, swizzled (W is [p][e][d])

    // XCD-aware chunk swizzle (NWG % 8 == 0): 16 M-blocks of one pair stay on
    // one XCD -> W[p] is L2-hot across its 16 consumers.
    int bid = blockIdx.x;
    int wg  = (bid & 7) * (NWG / 8) + (bid >> 3);
    int p   = wg >> 4;          // pair index 0..495
    int mb  = wg & 15;          // M-block 0..15

    // pair -> (i, j) per lexicographic combinations(range(32), 2)
    int fi = 0, rem = p;
    while (rem >= NF - 1 - fi) { rem -= NF - 1 - fi; ++fi; }
    int fj = fi + 1 + rem;

    const int t    = threadIdx.x;     // 0..511
    const int lane = t & 63;
    const int wave = t >> 6;          // 0..7
    const int b0   = mb * BM;

    // ---- Stage A: femb[b0+r][fi][d] -> bf16 LDS [r][d], swizzled ----
    #pragma unroll
    for (int it = 0; it < 4; ++it) {
        int idx8 = it * 4096 + t * 8;
        int r = idx8 >> 7;            // 0..127
        int d = idx8 & 127;           // multiple of 8
        const float* s = femb + ((size_t)(b0 + r) * NF + fi) * ED + d;
        float4 lo = *reinterpret_cast<const float4*>(s);
        float4 hi = *reinterpret_cast<const float4*>(s + 4);
        short8 pk;
        pk[0] = f2bf(lo.x); pk[1] = f2bf(lo.y);
        pk[2] = f2bf(lo.z); pk[3] = f2bf(lo.w);
        pk[4] = f2bf(hi.x); pk[5] = f2bf(hi.y);
        pk[6] = f2bf(hi.z); pk[7] = f2bf(hi.w);
        int byte = r * 256 + ((d * 2) ^ ((r & 15) << 4));
        *reinterpret_cast<short8*>(ldsA + byte) = pk;
    }

    // ---- Stage B: W[p][e][d] -> bf16 LDS [e][d], swizzled (no transpose) ----
    {
        const float* wp = W + (size_t)p * (ED * ED);
        #pragma unroll
        for (int it = 0; it < 4; ++it) {
            int idx8 = it * 4096 + t * 8;
            int e = idx8 >> 7;
            int d = idx8 & 127;
            const float* s = wp + (size_t)e * ED + d;
            float4 lo = *reinterpret_cast<const float4*>(s);
            float4 hi = *reinterpret_cast<const float4*>(s + 4);
            short8 pk;
            pk[0] = f2bf(lo.x); pk[1] = f2bf(lo.y);
            pk[2] = f2bf(lo.z); pk[3] = f2bf(lo.w);
            pk[4] = f2bf(hi.x); pk[5] = f2bf(hi.y);
            pk[6] = f2bf(hi.z); pk[7] = f2bf(hi.w);
            int byte = e * 256 + ((d * 2) ^ ((e & 15) << 4));
            *reinterpret_cast<short8*>(ldsB + byte) = pk;
        }
    }

    __syncthreads();

    // ---- Compute: D[e][b] = W . vi^T  (A-operand = W-frag, B-operand = vi-frag)
    // Wave grid: 4 e-quadrants (32 rows) x 2 b-halves (64 cols).
    const int we  = wave & 3;       // e-quadrant 0..3 (32 rows each)
    const int wb  = wave >> 2;      // b-half 0..1 (64 cols each)
    const int lhi = lane >> 4;      // 0..3
    const int llo = lane & 15;      // 0..15

    f32x4 acc[2][4] = {};           // [e-tile][b-tile]

    #pragma unroll
    for (int kk = 0; kk < 4; ++kk) {
        const int db = kk * 64 + lhi * 16;   // k-offset in bytes (k = kk*32 + lhi*8)
        short8 a[2], b[4];
        #pragma unroll
        for (int mi = 0; mi < 2; ++mi) {
            int e = we * 32 + mi * 16 + llo;           // e & 15 == llo
            a[mi] = *reinterpret_cast<const short8*>(ldsB + e * 256 + (db ^ (llo << 4)));
        }
        #pragma unroll
        for (int ni = 0; ni < 4; ++ni) {
            int r = wb * 64 + ni * 16 + llo;           // r & 15 == llo
            b[ni] = *reinterpret_cast<const short8*>(ldsA + r * 256 + (db ^ (llo << 4)));
        }
        #pragma unroll
        for (int mi = 0; mi < 2; ++mi)
            #pragma unroll
            for (int ni = 0; ni < 4; ++ni)
                acc[mi][ni] = __builtin_amdgcn_mfma_f32_16x16x32_bf16(a[mi], b[ni], acc[mi][ni], 0, 0, 0);
    }

    // ---- Epilogue: out[b][p][e] = D[e][b] * femb[b][fj][e], float4-vectorized ----
    // D frag: row(e-local) = lhi*4 + q, col(b-local) = llo  ->  lane holds 4
    // CONSECUTIVE e per fragment -> float4 load/store. Per store instruction,
    // lanes {llo, llo+16, llo+32, llo+48} fully cover one 64B line of row b.
    #pragma unroll
    for (int ni = 0; ni < 4; ++ni) {
        int b = b0 + wb * 64 + ni * 16 + llo;
        const float* vj = femb + ((size_t)b * NF + fj) * ED;
        float* op = out + ((size_t)b * NPAIRS + p) * ED;
        #pragma unroll
        for (int mi = 0; mi < 2; ++mi) {
            int e0 = we * 32 + mi * 16 + lhi * 4;
            float4 v = *reinterpret_cast<const float4*>(vj + e0);
            f32x4 r = acc[mi][ni];
            float4 o;
            o.x = r[0] * v.x; o.y = r[1] * v.y;
            o.z = r[2] * v.z; o.w = r[3] * v.w;
            *reinterpret_cast<float4*>(op + e0) = o;
        }
    }
}

extern "C" void kernel_launch(void* const* d_in, const int* in_sizes, int n_in,
                              void* d_out, int out_size, void* d_ws, size_t ws_size,
                              hipStream_t stream) {
    (void)in_sizes; (void)n_in; (void)out_size; (void)d_ws; (void)ws_size;
    const float* femb = (const float*)d_in[0];
    const float* W    = (const float*)d_in[1];
    float* out        = (float*)d_out;
    hipLaunchKernelGGL(bilinear_mfma_kernel, dim3(NWG), dim3(512), 0, stream,
                       femb, W, out);
}

// Round 4
// 222.765 us; speedup vs baseline: 1.0610x; 1.0610x over previous
//
#include <hip/hip_runtime.h>
#include <hip/hip_bf16.h>

#define NF     32
#define ED     128
#define NBATCH 2048
#define NPAIRS 496
#define BM     128
#define NITER  (NBATCH / BM)   // 16 M-blocks per pair, looped inside one block

typedef __attribute__((ext_vector_type(8))) short short8;   // 8 bf16 (MFMA A/B frag)
typedef __attribute__((ext_vector_type(4))) float f32x4;    // MFMA C/D frag

// Native cast -> compiler emits v_cvt_pk_bf16_f32 for pairs (m240)
__device__ __forceinline__ short f2bf(float x) {
    union { __hip_bfloat16 b; short s; } v;
    v.b = __float2bfloat16(x);
    return v.s;
}

// LDS byte layout (both tiles): 128 rows x 256 B, swizzled:
//   byte(row, col) = row*256 + (col ^ ((row & 15) << 4))
// -> fragment reads (16 lanes, 16 consecutive rows, same col slot) hit 16
//    distinct 16B slots => conflict-free ds_read_b128.

__global__ __launch_bounds__(512, 2)
void bilinear_mfma_kernel(const float* __restrict__ femb,
                          const float* __restrict__ W,
                          float* __restrict__ out)
{
    __shared__ unsigned char ldsW[128 * 256];  // W[p] tile [e][d] bf16, staged ONCE
    __shared__ unsigned char ldsA[128 * 256];  // vi tile [b_local][d] bf16, per iteration

    const int p = blockIdx.x;                  // one block per pair, persistent
    int fi = 0, rem = p;
    while (rem >= NF - 1 - fi) { rem -= NF - 1 - fi; ++fi; }
    const int fj = fi + 1 + rem;

    const int t    = threadIdx.x;              // 0..511
    const int lane = t & 63;
    const int wave = t >> 6;                   // 0..7

    // ---- Stage W once: W[p][e][d] fp32 -> bf16 LDS [e][d], swizzled ----
    {
        const float* wp = W + (size_t)p * (ED * ED);
        #pragma unroll
        for (int it = 0; it < 4; ++it) {
            int idx8 = it * 4096 + t * 8;
            int e = idx8 >> 7, d = idx8 & 127;
            const float* s = wp + (size_t)e * ED + d;
            float4 lo = *reinterpret_cast<const float4*>(s);
            float4 hi = *reinterpret_cast<const float4*>(s + 4);
            short8 pk;
            pk[0]=f2bf(lo.x); pk[1]=f2bf(lo.y); pk[2]=f2bf(lo.z); pk[3]=f2bf(lo.w);
            pk[4]=f2bf(hi.x); pk[5]=f2bf(hi.y); pk[6]=f2bf(hi.z); pk[7]=f2bf(hi.w);
            *reinterpret_cast<short8*>(ldsW + e * 256 + ((d * 2) ^ ((e & 15) << 4))) = pk;
        }
    }

    // Per-thread vi staging coords (constant across iterations):
    // thread covers rows {r_, r_+32, r_+64, r_+96} at d_ .. d_+7.
    const int r_ = t >> 4;            // 0..31
    const int d_ = (t * 8) & 127;     // 0..120, step 8
    const size_t ROWSTRIDE32 = (size_t)32 * NF * ED;   // +32 batch rows in femb

    // Wave tiling: D[e][b], 4 e-quadrants (32 rows) x 2 b-halves (64 cols)
    const int we  = wave & 3;
    const int wb  = wave >> 2;
    const int lhi = lane >> 4;
    const int llo = lane & 15;

    float4 stg[8];   // prefetched vi for the NEXT A-write (4 rows x {lo,hi})

    // Prefetch vi for mb = 0
    {
        const float* base = femb + ((size_t)r_ * NF + fi) * ED + d_;
        #pragma unroll
        for (int q = 0; q < 4; ++q) {
            const float* s = base + (size_t)q * ROWSTRIDE32;
            stg[2*q]   = *reinterpret_cast<const float4*>(s);
            stg[2*q+1] = *reinterpret_cast<const float4*>(s + 4);
        }
    }

    for (int mb = 0; mb < NITER; ++mb) {
        const int b0 = mb * BM;

        // ---- A-write: staged vi regs -> bf16 LDS [r][d], swizzled ----
        #pragma unroll
        for (int q = 0; q < 4; ++q) {
            int r = r_ + q * 32;
            float4 lo = stg[2*q], hi = stg[2*q+1];
            short8 pk;
            pk[0]=f2bf(lo.x); pk[1]=f2bf(lo.y); pk[2]=f2bf(lo.z); pk[3]=f2bf(lo.w);
            pk[4]=f2bf(hi.x); pk[5]=f2bf(hi.y); pk[6]=f2bf(hi.z); pk[7]=f2bf(hi.w);
            *reinterpret_cast<short8*>(ldsA + r * 256 + ((d_ * 2) ^ ((r & 15) << 4))) = pk;
        }
        __syncthreads();   // A (and W on first iter) visible to all waves

        // ---- Issue next vi prefetch (latency hidden under MFMA cluster) ----
        if (mb + 1 < NITER) {
            const float* base = femb + ((size_t)((mb + 1) * BM + r_) * NF + fi) * ED + d_;
            #pragma unroll
            for (int q = 0; q < 4; ++q) {
                const float* s = base + (size_t)q * ROWSTRIDE32;
                stg[2*q]   = *reinterpret_cast<const float4*>(s);
                stg[2*q+1] = *reinterpret_cast<const float4*>(s + 4);
            }
        }

        // ---- Prefetch vj rows for the epilogue ----
        float4 vjr[4][2];
        #pragma unroll
        for (int ni = 0; ni < 4; ++ni) {
            int b = b0 + wb * 64 + ni * 16 + llo;
            const float* vj = femb + ((size_t)b * NF + fj) * ED;
            #pragma unroll
            for (int mi = 0; mi < 2; ++mi) {
                int e0 = we * 32 + mi * 16 + lhi * 4;
                vjr[ni][mi] = *reinterpret_cast<const float4*>(vj + e0);
            }
        }

        // ---- Compute: D[e][b] = W . vi^T ----
        f32x4 acc[2][4] = {};
        #pragma unroll
        for (int kk = 0; kk < 4; ++kk) {
            const int db = kk * 64 + lhi * 16;
            short8 a[2], b[4];
            #pragma unroll
            for (int mi = 0; mi < 2; ++mi) {
                int e = we * 32 + mi * 16 + llo;
                a[mi] = *reinterpret_cast<const short8*>(ldsW + e * 256 + (db ^ (llo << 4)));
            }
            #pragma unroll
            for (int ni = 0; ni < 4; ++ni) {
                int r = wb * 64 + ni * 16 + llo;
                b[ni] = *reinterpret_cast<const short8*>(ldsA + r * 256 + (db ^ (llo << 4)));
            }
            #pragma unroll
            for (int mi = 0; mi < 2; ++mi)
                #pragma unroll
                for (int ni = 0; ni < 4; ++ni)
                    acc[mi][ni] = __builtin_amdgcn_mfma_f32_16x16x32_bf16(a[mi], b[ni], acc[mi][ni], 0, 0, 0);
        }
        __syncthreads();   // all ds_reads of ldsA done -> next iter may overwrite

        // ---- Epilogue: out[b][p][e] = D[e][b] * vj[e], float4 stores ----
        // D frag: row(e-local) = lhi*4+q, col(b-local) = llo; lanes
        // {llo,llo+16,llo+32,llo+48} fully cover one 64B line per store.
        #pragma unroll
        for (int ni = 0; ni < 4; ++ni) {
            int b = b0 + wb * 64 + ni * 16 + llo;
            float* op = out + ((size_t)b * NPAIRS + p) * ED;
            #pragma unroll
            for (int mi = 0; mi < 2; ++mi) {
                int e0 = we * 32 + mi * 16 + lhi * 4;
                float4 v = vjr[ni][mi];
                f32x4 r = acc[mi][ni];
                float4 o;
                o.x = r[0] * v.x; o.y = r[1] * v.y;
                o.z = r[2] * v.z; o.w = r[3] * v.w;
                *reinterpret_cast<float4*>(op + e0) = o;
            }
        }
    }
}

extern "C" void kernel_launch(void* const* d_in, const int* in_sizes, int n_in,
                              void* d_out, int out_size, void* d_ws, size_t ws_size,
                              hipStream_t stream) {
    (void)in_sizes; (void)n_in; (void)out_size; (void)d_ws; (void)ws_size;
    const float* femb = (const float*)d_in[0];
    const float* W    = (const float*)d_in[1];
    float* out        = (float*)d_out;
    hipLaunchKernelGGL(bilinear_mfma_kernel, dim3(NPAIRS), dim3(512), 0, stream,
                       femb, W, out);
}

// Round 6
// 199.342 us; speedup vs baseline: 1.1857x; 1.1175x over previous
//
#include <hip/hip_runtime.h>
#include <hip/hip_bf16.h>

#define NF     32
#define ED     128
#define NBATCH 2048
#define NPAIRS 496
#define BM     128
#define NITER  (NBATCH / BM)   // 16 M-blocks per pair, looped inside one block

typedef __attribute__((ext_vector_type(8))) short short8;   // 8 bf16 (MFMA A/B frag)
typedef __attribute__((ext_vector_type(4))) float f32x4;    // clang vector: ok for nontemporal builtins

// Native cast -> compiler emits v_cvt_pk_bf16_f32 for pairs (m240)
__device__ __forceinline__ short f2bf(float x) {
    union { __hip_bfloat16 b; short s; } v;
    v.b = __float2bfloat16(x);
    return v.s;
}

// LDS byte layout (both tiles): 128 rows x 256 B, swizzled:
//   byte(row, col) = row*256 + (col ^ ((row & 15) << 4))
// -> fragment reads (16 lanes, 16 consecutive rows, same col slot) hit 16
//    distinct 16B slots => conflict-free ds_read_b128.

__global__ __launch_bounds__(512, 2)
void bilinear_mfma_kernel(const float* __restrict__ femb,
                          const float* __restrict__ W,
                          float* __restrict__ out)
{
    __shared__ unsigned char ldsW[128 * 256];  // W[p] tile [e][d] bf16, staged ONCE
    __shared__ unsigned char ldsA[128 * 256];  // vi tile [b_local][d] bf16, per iteration

    const int p = blockIdx.x;                  // one block per pair, persistent
    int fi = 0, rem = p;
    while (rem >= NF - 1 - fi) { rem -= NF - 1 - fi; ++fi; }
    const int fj = fi + 1 + rem;

    const int t    = threadIdx.x;              // 0..511
    const int lane = t & 63;
    const int wave = t >> 6;                   // 0..7

    // ---- Stage W once: W[p][e][d] fp32 -> bf16 LDS [e][d], swizzled ----
    // Read-once data: non-temporal loads, don't pollute L2.
    {
        const float* wp = W + (size_t)p * (ED * ED);
        #pragma unroll
        for (int it = 0; it < 4; ++it) {
            int idx8 = it * 4096 + t * 8;
            int e = idx8 >> 7, d = idx8 & 127;
            const float* s = wp + (size_t)e * ED + d;
            f32x4 lo = __builtin_nontemporal_load(reinterpret_cast<const f32x4*>(s));
            f32x4 hi = __builtin_nontemporal_load(reinterpret_cast<const f32x4*>(s + 4));
            short8 pk;
            pk[0]=f2bf(lo.x); pk[1]=f2bf(lo.y); pk[2]=f2bf(lo.z); pk[3]=f2bf(lo.w);
            pk[4]=f2bf(hi.x); pk[5]=f2bf(hi.y); pk[6]=f2bf(hi.z); pk[7]=f2bf(hi.w);
            *reinterpret_cast<short8*>(ldsW + e * 256 + ((d * 2) ^ ((e & 15) << 4))) = pk;
        }
    }

    // Per-thread vi staging coords (constant across iterations):
    // thread covers rows {r_, r_+32, r_+64, r_+96} at d_ .. d_+7.
    const int r_ = t >> 4;            // 0..31
    const int d_ = (t * 8) & 127;     // 0..120, step 8
    const size_t ROWSTRIDE32 = (size_t)32 * NF * ED;   // +32 batch rows in femb

    // Wave tiling: D[e][b], 4 e-quadrants (32 rows) x 2 b-halves (64 cols)
    const int we  = wave & 3;
    const int wb  = wave >> 2;
    const int lhi = lane >> 4;
    const int llo = lane & 15;

    f32x4 stg[8];   // prefetched vi for the NEXT A-write (4 rows x {lo,hi})

    // Prefetch vi for mb = 0
    {
        const float* base = femb + ((size_t)r_ * NF + fi) * ED + d_;
        #pragma unroll
        for (int q = 0; q < 4; ++q) {
            const float* s = base + (size_t)q * ROWSTRIDE32;
            stg[2*q]   = *reinterpret_cast<const f32x4*>(s);
            stg[2*q+1] = *reinterpret_cast<const f32x4*>(s + 4);
        }
    }

    for (int mb = 0; mb < NITER; ++mb) {
        const int b0 = mb * BM;

        // ---- A-write: staged vi regs -> bf16 LDS [r][d], swizzled ----
        #pragma unroll
        for (int q = 0; q < 4; ++q) {
            int r = r_ + q * 32;
            f32x4 lo = stg[2*q], hi = stg[2*q+1];
            short8 pk;
            pk[0]=f2bf(lo.x); pk[1]=f2bf(lo.y); pk[2]=f2bf(lo.z); pk[3]=f2bf(lo.w);
            pk[4]=f2bf(hi.x); pk[5]=f2bf(hi.y); pk[6]=f2bf(hi.z); pk[7]=f2bf(hi.w);
            *reinterpret_cast<short8*>(ldsA + r * 256 + ((d_ * 2) ^ ((r & 15) << 4))) = pk;
        }
        __syncthreads();   // A (and W on first iter) visible to all waves

        // ---- Issue next vi prefetch (latency hidden under MFMA cluster) ----
        if (mb + 1 < NITER) {
            const float* base = femb + ((size_t)((mb + 1) * BM + r_) * NF + fi) * ED + d_;
            #pragma unroll
            for (int q = 0; q < 4; ++q) {
                const float* s = base + (size_t)q * ROWSTRIDE32;
                stg[2*q]   = *reinterpret_cast<const f32x4*>(s);
                stg[2*q+1] = *reinterpret_cast<const f32x4*>(s + 4);
            }
        }

        // ---- Prefetch vj rows for the epilogue (want these L2-cached) ----
        f32x4 vjr[4][2];
        #pragma unroll
        for (int ni = 0; ni < 4; ++ni) {
            int b = b0 + wb * 64 + ni * 16 + llo;
            const float* vj = femb + ((size_t)b * NF + fj) * ED;
            #pragma unroll
            for (int mi = 0; mi < 2; ++mi) {
                int e0 = we * 32 + mi * 16 + lhi * 4;
                vjr[ni][mi] = *reinterpret_cast<const f32x4*>(vj + e0);
            }
        }

        // ---- Compute: D[e][b] = W . vi^T ----
        f32x4 acc[2][4] = {};
        #pragma unroll
        for (int kk = 0; kk < 4; ++kk) {
            const int db = kk * 64 + lhi * 16;
            short8 a[2], b[4];
            #pragma unroll
            for (int mi = 0; mi < 2; ++mi) {
                int e = we * 32 + mi * 16 + llo;
                a[mi] = *reinterpret_cast<const short8*>(ldsW + e * 256 + (db ^ (llo << 4)));
            }
            #pragma unroll
            for (int ni = 0; ni < 4; ++ni) {
                int r = wb * 64 + ni * 16 + llo;
                b[ni] = *reinterpret_cast<const short8*>(ldsA + r * 256 + (db ^ (llo << 4)));
            }
            #pragma unroll
            for (int mi = 0; mi < 2; ++mi)
                #pragma unroll
                for (int ni = 0; ni < 4; ++ni)
                    acc[mi][ni] = __builtin_amdgcn_mfma_f32_16x16x32_bf16(a[mi], b[ni], acc[mi][ni], 0, 0, 0);
        }
        __syncthreads();   // all ds_reads of ldsA done -> next iter may overwrite

        // ---- Epilogue: out[b][p][e] = D[e][b] * vj[e] ----
        // NON-TEMPORAL stores: 520 MB write stream must not thrash L2 —
        // the femb phase-slice (2 MB/XCD) has to survive in L2 so the next
        // phase's vi/vj reads are L2 hits instead of riding the L3 fabric.
        #pragma unroll
        for (int ni = 0; ni < 4; ++ni) {
            int b = b0 + wb * 64 + ni * 16 + llo;
            float* op = out + ((size_t)b * NPAIRS + p) * ED;
            #pragma unroll
            for (int mi = 0; mi < 2; ++mi) {
                int e0 = we * 32 + mi * 16 + lhi * 4;
                f32x4 v = vjr[ni][mi];
                f32x4 r = acc[mi][ni];
                f32x4 o;
                o.x = r[0] * v.x; o.y = r[1] * v.y;
                o.z = r[2] * v.z; o.w = r[3] * v.w;
                __builtin_nontemporal_store(o, reinterpret_cast<f32x4*>(op + e0));
            }
        }
    }
}

extern "C" void kernel_launch(void* const* d_in, const int* in_sizes, int n_in,
                              void* d_out, int out_size, void* d_ws, size_t ws_size,
                              hipStream_t stream) {
    (void)in_sizes; (void)n_in; (void)out_size; (void)d_ws; (void)ws_size;
    const float* femb = (const float*)d_in[0];
    const float* W    = (const float*)d_in[1];
    float* out        = (float*)d_out;
    hipLaunchKernelGGL(bilinear_mfma_kernel, dim3(NPAIRS), dim3(512), 0, stream,
                       femb, W, out);
}

// Round 7
// 188.003 us; speedup vs baseline: 1.2572x; 1.0603x over previous
//
#include <hip/hip_runtime.h>
#include <hip/hip_bf16.h>

#define NF     32
#define ED     128
#define NBATCH 2048
#define NPAIRS 496
#define BM     128
#define NITER  (NBATCH / BM)   // 16 M-blocks per pair

typedef __attribute__((ext_vector_type(8))) short short8;   // 8 bf16 (MFMA A/B frag)
typedef __attribute__((ext_vector_type(4))) short short4v;  // 4 bf16
typedef __attribute__((ext_vector_type(4))) float f32x4;

#define FEMB_BF_ELEMS ((size_t)NF * NBATCH * ED)            // 8,388,608
#define W_BF_ELEMS    ((size_t)NPAIRS * ED * ED)            // 8,126,464
#define WS_NEEDED     ((FEMB_BF_ELEMS + W_BF_ELEMS) * 2)    // ~33 MB

__device__ __forceinline__ short f2bf(float x) {
    union { __hip_bfloat16 b; short s; } v;
    v.b = __float2bfloat16(x);
    return v.s;
}
__device__ __forceinline__ float bf2f(short s) {
    union { unsigned int u; float f; } v;
    v.u = ((unsigned int)(unsigned short)s) << 16;
    return v.f;
}

// ---------- Pre-pass 1: femb fp32 [b][f][d] -> bf16 field-major [f][b][d] ----------
__global__ __launch_bounds__(256)
void prep_femb(const float* __restrict__ femb, unsigned short* __restrict__ fb) {
    int n = blockIdx.x * 256 + threadIdx.x;       // 1,048,576 threads x 8 elems
    int d8 = n & 15;
    int b  = (n >> 4) & (NBATCH - 1);
    int f  = n >> 15;
    const float* s = femb + ((size_t)b * NF + f) * ED + d8 * 8;
    f32x4 lo = __builtin_nontemporal_load(reinterpret_cast<const f32x4*>(s));
    f32x4 hi = __builtin_nontemporal_load(reinterpret_cast<const f32x4*>(s + 4));
    short8 pk;
    pk[0]=f2bf(lo.x); pk[1]=f2bf(lo.y); pk[2]=f2bf(lo.z); pk[3]=f2bf(lo.w);
    pk[4]=f2bf(hi.x); pk[5]=f2bf(hi.y); pk[6]=f2bf(hi.z); pk[7]=f2bf(hi.w);
    *reinterpret_cast<short8*>(fb + ((size_t)f * NBATCH + b) * ED + d8 * 8) = pk;
}

// ---------- Pre-pass 2: W fp32 -> bf16 flat [p][e][d] ----------
__global__ __launch_bounds__(256)
void prep_w(const float* __restrict__ W, unsigned short* __restrict__ wb) {
    size_t n = (size_t)blockIdx.x * 256 + threadIdx.x;
    size_t idx8 = n * 8;
    if (idx8 >= W_BF_ELEMS) return;
    const float* s = W + idx8;
    f32x4 lo = __builtin_nontemporal_load(reinterpret_cast<const f32x4*>(s));
    f32x4 hi = __builtin_nontemporal_load(reinterpret_cast<const f32x4*>(s + 4));
    short8 pk;
    pk[0]=f2bf(lo.x); pk[1]=f2bf(lo.y); pk[2]=f2bf(lo.z); pk[3]=f2bf(lo.w);
    pk[4]=f2bf(hi.x); pk[5]=f2bf(hi.y); pk[6]=f2bf(hi.z); pk[7]=f2bf(hi.w);
    *reinterpret_cast<short8*>(wb + idx8) = pk;
}

// LDS layout (both tiles): 128 rows x 256 B, swizzled:
//   byte(row, col) = row*256 + (col ^ ((row & 15) << 4))   -> conflict-free ds_read_b128

// ---------- Main kernel, bf16 inputs from ws ----------
__global__ __launch_bounds__(512, 2)
void bilinear_bf16(const unsigned short* __restrict__ fb,
                   const unsigned short* __restrict__ wb,
                   float* __restrict__ out)
{
    __shared__ unsigned char ldsW[128 * 256];
    __shared__ unsigned char ldsA[128 * 256];

    const int p = blockIdx.x;
    int fi = 0, rem = p;
    while (rem >= NF - 1 - fi) { rem -= NF - 1 - fi; ++fi; }
    const int fj = fi + 1 + rem;

    const int t    = threadIdx.x;
    const int lane = t & 63;
    const int wave = t >> 6;

    // ---- Stage W once: bf16, read-once (NT), swizzled LDS write ----
    {
        const unsigned short* wp = wb + (size_t)p * (ED * ED);
        #pragma unroll
        for (int it = 0; it < 4; ++it) {
            int idx8 = it * 4096 + t * 8;
            int e = idx8 >> 7, d = idx8 & 127;
            short8 pk = __builtin_nontemporal_load(
                reinterpret_cast<const short8*>(wp + idx8));
            *reinterpret_cast<short8*>(ldsW + e * 256 + ((d * 2) ^ ((e & 15) << 4))) = pk;
        }
    }

    // vi staging coords: thread covers rows {r_, r_+32, r_+64, r_+96} at d_..d_+7
    const int r_ = t >> 4;
    const int d_ = (t * 8) & 127;
    const unsigned short* fiPlane = fb + (size_t)fi * NBATCH * ED;
    const unsigned short* fjPlane = fb + (size_t)fj * NBATCH * ED;

    const int we  = wave & 3;       // e-quadrant
    const int wb_ = wave >> 2;      // b-half
    const int lhi = lane >> 4;
    const int llo = lane & 15;

    short8 stg[4];
    #pragma unroll
    for (int q = 0; q < 4; ++q)
        stg[q] = *reinterpret_cast<const short8*>(fiPlane + (size_t)(r_ + q * 32) * ED + d_);

    for (int mb = 0; mb < NITER; ++mb) {
        const int b0 = mb * BM;

        // ---- A-write: staged bf16 -> swizzled LDS (no cvt) ----
        #pragma unroll
        for (int q = 0; q < 4; ++q) {
            int r = r_ + q * 32;
            *reinterpret_cast<short8*>(ldsA + r * 256 + ((d_ * 2) ^ ((r & 15) << 4))) = stg[q];
        }
        __syncthreads();

        // ---- Issue next vi prefetch ----
        if (mb + 1 < NITER) {
            const unsigned short* base = fiPlane + (size_t)((mb + 1) * BM + r_) * ED + d_;
            #pragma unroll
            for (int q = 0; q < 4; ++q)
                stg[q] = *reinterpret_cast<const short8*>(base + (size_t)q * 32 * ED);
        }

        // ---- Prefetch vj (bf16) for epilogue ----
        short4v vjr[4][2];
        #pragma unroll
        for (int ni = 0; ni < 4; ++ni) {
            int b = b0 + wb_ * 64 + ni * 16 + llo;
            const unsigned short* vj = fjPlane + (size_t)b * ED;
            #pragma unroll
            for (int mi = 0; mi < 2; ++mi) {
                int e0 = we * 32 + mi * 16 + lhi * 4;
                vjr[ni][mi] = *reinterpret_cast<const short4v*>(vj + e0);
            }
        }

        // ---- Compute: D[e][b] = W . vi^T ----
        f32x4 acc[2][4] = {};
        #pragma unroll
        for (int kk = 0; kk < 4; ++kk) {
            const int db = kk * 64 + lhi * 16;
            short8 a[2], b[4];
            #pragma unroll
            for (int mi = 0; mi < 2; ++mi) {
                int e = we * 32 + mi * 16 + llo;
                a[mi] = *reinterpret_cast<const short8*>(ldsW + e * 256 + (db ^ (llo << 4)));
            }
            #pragma unroll
            for (int ni = 0; ni < 4; ++ni) {
                int r = wb_ * 64 + ni * 16 + llo;
                b[ni] = *reinterpret_cast<const short8*>(ldsA + r * 256 + (db ^ (llo << 4)));
            }
            #pragma unroll
            for (int mi = 0; mi < 2; ++mi)
                #pragma unroll
                for (int ni = 0; ni < 4; ++ni)
                    acc[mi][ni] = __builtin_amdgcn_mfma_f32_16x16x32_bf16(a[mi], b[ni], acc[mi][ni], 0, 0, 0);
        }
        __syncthreads();

        // ---- Epilogue: out = D * vj, NT stores ----
        #pragma unroll
        for (int ni = 0; ni < 4; ++ni) {
            int b = b0 + wb_ * 64 + ni * 16 + llo;
            float* op = out + ((size_t)b * NPAIRS + p) * ED;
            #pragma unroll
            for (int mi = 0; mi < 2; ++mi) {
                int e0 = we * 32 + mi * 16 + lhi * 4;
                short4v vs = vjr[ni][mi];
                f32x4 r = acc[mi][ni];
                f32x4 o;
                o.x = r[0] * bf2f(vs[0]); o.y = r[1] * bf2f(vs[1]);
                o.z = r[2] * bf2f(vs[2]); o.w = r[3] * bf2f(vs[3]);
                __builtin_nontemporal_store(o, reinterpret_cast<f32x4*>(op + e0));
            }
        }
    }
}

// ---------- Fallback (round-6 kernel, fp32 inputs) if ws too small ----------
__global__ __launch_bounds__(512, 2)
void bilinear_f32(const float* __restrict__ femb,
                  const float* __restrict__ W,
                  float* __restrict__ out)
{
    __shared__ unsigned char ldsW[128 * 256];
    __shared__ unsigned char ldsA[128 * 256];

    const int p = blockIdx.x;
    int fi = 0, rem = p;
    while (rem >= NF - 1 - fi) { rem -= NF - 1 - fi; ++fi; }
    const int fj = fi + 1 + rem;

    const int t    = threadIdx.x;
    const int lane = t & 63;
    const int wave = t >> 6;

    {
        const float* wp = W + (size_t)p * (ED * ED);
        #pragma unroll
        for (int it = 0; it < 4; ++it) {
            int idx8 = it * 4096 + t * 8;
            int e = idx8 >> 7, d = idx8 & 127;
            const float* s = wp + (size_t)e * ED + d;
            f32x4 lo = __builtin_nontemporal_load(reinterpret_cast<const f32x4*>(s));
            f32x4 hi = __builtin_nontemporal_load(reinterpret_cast<const f32x4*>(s + 4));
            short8 pk;
            pk[0]=f2bf(lo.x); pk[1]=f2bf(lo.y); pk[2]=f2bf(lo.z); pk[3]=f2bf(lo.w);
            pk[4]=f2bf(hi.x); pk[5]=f2bf(hi.y); pk[6]=f2bf(hi.z); pk[7]=f2bf(hi.w);
            *reinterpret_cast<short8*>(ldsW + e * 256 + ((d * 2) ^ ((e & 15) << 4))) = pk;
        }
    }

    const int r_ = t >> 4;
    const int d_ = (t * 8) & 127;
    const size_t ROWSTRIDE32 = (size_t)32 * NF * ED;

    const int we  = wave & 3;
    const int wb_ = wave >> 2;
    const int lhi = lane >> 4;
    const int llo = lane & 15;

    f32x4 stg[8];
    {
        const float* base = femb + ((size_t)r_ * NF + fi) * ED + d_;
        #pragma unroll
        for (int q = 0; q < 4; ++q) {
            const float* s = base + (size_t)q * ROWSTRIDE32;
            stg[2*q]   = *reinterpret_cast<const f32x4*>(s);
            stg[2*q+1] = *reinterpret_cast<const f32x4*>(s + 4);
        }
    }

    for (int mb = 0; mb < NITER; ++mb) {
        const int b0 = mb * BM;
        #pragma unroll
        for (int q = 0; q < 4; ++q) {
            int r = r_ + q * 32;
            f32x4 lo = stg[2*q], hi = stg[2*q+1];
            short8 pk;
            pk[0]=f2bf(lo.x); pk[1]=f2bf(lo.y); pk[2]=f2bf(lo.z); pk[3]=f2bf(lo.w);
            pk[4]=f2bf(hi.x); pk[5]=f2bf(hi.y); pk[6]=f2bf(hi.z); pk[7]=f2bf(hi.w);
            *reinterpret_cast<short8*>(ldsA + r * 256 + ((d_ * 2) ^ ((r & 15) << 4))) = pk;
        }
        __syncthreads();

        if (mb + 1 < NITER) {
            const float* base = femb + ((size_t)((mb + 1) * BM + r_) * NF + fi) * ED + d_;
            #pragma unroll
            for (int q = 0; q < 4; ++q) {
                const float* s = base + (size_t)q * ROWSTRIDE32;
                stg[2*q]   = *reinterpret_cast<const f32x4*>(s);
                stg[2*q+1] = *reinterpret_cast<const f32x4*>(s + 4);
            }
        }

        f32x4 vjr[4][2];
        #pragma unroll
        for (int ni = 0; ni < 4; ++ni) {
            int b = b0 + wb_ * 64 + ni * 16 + llo;
            const float* vj = femb + ((size_t)b * NF + fj) * ED;
            #pragma unroll
            for (int mi = 0; mi < 2; ++mi) {
                int e0 = we * 32 + mi * 16 + lhi * 4;
                vjr[ni][mi] = *reinterpret_cast<const f32x4*>(vj + e0);
            }
        }

        f32x4 acc[2][4] = {};
        #pragma unroll
        for (int kk = 0; kk < 4; ++kk) {
            const int db = kk * 64 + lhi * 16;
            short8 a[2], b[4];
            #pragma unroll
            for (int mi = 0; mi < 2; ++mi) {
                int e = we * 32 + mi * 16 + llo;
                a[mi] = *reinterpret_cast<const short8*>(ldsW + e * 256 + (db ^ (llo << 4)));
            }
            #pragma unroll
            for (int ni = 0; ni < 4; ++ni) {
                int r = wb_ * 64 + ni * 16 + llo;
                b[ni] = *reinterpret_cast<const short8*>(ldsA + r * 256 + (db ^ (llo << 4)));
            }
            #pragma unroll
            for (int mi = 0; mi < 2; ++mi)
                #pragma unroll
                for (int ni = 0; ni < 4; ++ni)
                    acc[mi][ni] = __builtin_amdgcn_mfma_f32_16x16x32_bf16(a[mi], b[ni], acc[mi][ni], 0, 0, 0);
        }
        __syncthreads();

        #pragma unroll
        for (int ni = 0; ni < 4; ++ni) {
            int b = b0 + wb_ * 64 + ni * 16 + llo;
            float* op = out + ((size_t)b * NPAIRS + p) * ED;
            #pragma unroll
            for (int mi = 0; mi < 2; ++mi) {
                int e0 = we * 32 + mi * 16 + lhi * 4;
                f32x4 v = vjr[ni][mi];
                f32x4 r = acc[mi][ni];
                f32x4 o;
                o.x = r[0] * v.x; o.y = r[1] * v.y;
                o.z = r[2] * v.z; o.w = r[3] * v.w;
                __builtin_nontemporal_store(o, reinterpret_cast<f32x4*>(op + e0));
            }
        }
    }
}

extern "C" void kernel_launch(void* const* d_in, const int* in_sizes, int n_in,
                              void* d_out, int out_size, void* d_ws, size_t ws_size,
                              hipStream_t stream) {
    (void)in_sizes; (void)n_in; (void)out_size;
    const float* femb = (const float*)d_in[0];
    const float* W    = (const float*)d_in[1];
    float* out        = (float*)d_out;

    if (ws_size >= WS_NEEDED) {
        unsigned short* fb = (unsigned short*)d_ws;
        unsigned short* wbp = fb + FEMB_BF_ELEMS;
        hipLaunchKernelGGL(prep_femb, dim3(FEMB_BF_ELEMS / 8 / 256), dim3(256), 0, stream, femb, fb);
        hipLaunchKernelGGL(prep_w,    dim3((W_BF_ELEMS / 8 + 255) / 256), dim3(256), 0, stream, W, wbp);
        hipLaunchKernelGGL(bilinear_bf16, dim3(NPAIRS), dim3(512), 0, stream, fb, wbp, out);
    } else {
        hipLaunchKernelGGL(bilinear_f32, dim3(NPAIRS), dim3(512), 0, stream, femb, W, out);
    }
}